// Round 11
// baseline (128.234 us; speedup 1.0000x reference)
//
#include <hip/hip_runtime.h>
#include <math.h>

#define T_IN 64
#define NPIX 16384
#define MAX_ITER 10
#define NSLOT 43
#define MAGIC 0x13579BDFu

typedef _Float16 half8_t __attribute__((ext_vector_type(8)));
typedef __fp16   fp16x2  __attribute__((ext_vector_type(2)));
typedef float    f32x4   __attribute__((ext_vector_type(4)));
typedef int      i32x4   __attribute__((ext_vector_type(4)));

union H8 { half8_t v; fp16x2 h2[4]; i32x4 i4; };

__device__ __forceinline__ float rcp_fast(float x) { return __builtin_amdgcn_rcpf(x); }

constexpr int NTMIN[16]   = {0,0,0,0,0,1,1,1,1,2,2,2,2,3,3,3};
// K-split: parity 0 = even kt (23 slots), parity 1 = odd kt (20 slots)
constexpr int KTS[2][8]   = {{0,2,4,6,8,10,12,14},{1,3,5,7,9,11,13,15}};
constexpr int LBASE[2][8] = {{0,4,8,12,15,18,20,22},{0,4,8,11,14,16,18,19}};
constexpr int SLOTS[2][23] = {
  {0,1,2,3,8,9,10,11,16,17,18,19,23,24,25,29,30,31,34,35,38,39,41},
  {4,5,6,7,12,13,14,15,20,21,22,26,27,28,32,33,36,37,40,42,0,0,0}};

// ---- one K-half (parity P), all Breg/slot indices compile-time ----
template<int P>
__device__ __forceinline__ void kloop(float K, float T0, int q,
        const float* tshs, const i32x4 (&Breg)[23], f32x4 (&acc)[3][4]) {
    float nK = -K;
    float r  = __expf(0.125f * K);     // x ratio per t-step
    #pragma unroll
    for (int i = 0; i < 8; ++i) {
        const int kt = KTS[P][i];
        f32x4 tv0 = *(const f32x4*)&tshs[32*kt + 8*q];
        f32x4 tv1 = *(const f32x4*)&tshs[32*kt + 8*q + 4];
        float d1[8];
        d1[0]=T0-tv0[0]; d1[1]=T0-tv0[1]; d1[2]=T0-tv0[2]; d1[3]=T0-tv0[3];
        d1[4]=T0-tv1[0]; d1[5]=T0-tv1[1]; d1[6]=T0-tv1[2]; d1[7]=T0-tv1[3];
        float x[8];
        if (kt == 0 || kt == 15) {
            bool edge = (kt == 0) ? (q == 0) : (q == 3);  // flat tsh samples
            if (edge) {
                #pragma unroll
                for (int j = 0; j < 8; ++j) x[j] = __expf(nK * d1[j]);
            } else {
                x[0] = __expf(nK * d1[0]);
                #pragma unroll
                for (int j = 1; j < 8; ++j) x[j] = x[j-1] * r;
            }
        } else {
            x[0] = __expf(nK * d1[0]);
            #pragma unroll
            for (int j = 1; j < 8; ++j) x[j] = x[j-1] * r;
        }
        H8 F0h, F1h, F2h;
        #pragma unroll
        for (int jj = 0; jj < 4; ++jj) {
            float s1a = rcp_fast(1.0f + x[2*jj]);
            float s1b = rcp_fast(1.0f + x[2*jj+1]);
            fp16x2 sh  = (fp16x2){(__fp16)s1a, (__fp16)s1b};          // RTN
            fp16x2 d1h = __builtin_amdgcn_cvt_pkrtz(d1[2*jj], d1[2*jj+1]);
            fp16x2 eh  = sh - sh*sh;                                  // v_pk f16
            F0h.h2[jj] = sh;
            F1h.h2[jj] = eh * d1h;
            F2h.h2[jj] = eh;
        }
        #pragma unroll
        for (int nt = NTMIN[kt]; nt < 4; ++nt) {
            int sl = LBASE[P][i] + nt - NTMIN[kt];
            H8 bh; bh.i4 = Breg[sl];
            acc[0][nt] = __builtin_amdgcn_mfma_f32_16x16x32_f16(F0h.v, bh.v, acc[0][nt], 0, 0, 0);
            acc[1][nt] = __builtin_amdgcn_mfma_f32_16x16x32_f16(F1h.v, bh.v, acc[1][nt], 0, 0, 0);
            acc[2][nt] = __builtin_amdgcn_mfma_f32_16x16x32_f16(F2h.v, bh.v, acc[2][nt], 0, 0, 0);
        }
    }
}

// ---------------------------------------------------------------- all -------
// Single dispatch, 256 blocks x 512 threads (1 block/CU, 2 waves/SIMD).
// Wave pair (2p,2p+1): K-parity split; SYMMETRIC acc exchange through
// conflict-free padded LDS ([13] f32x4 -> lane stride 52 words,
// start banks 20*lane mod 32 = 8 distinct groups = no conflicts).
// Both waves run the epilogue redundantly (identical FP -> identical eta).
// cbuf unioned over Bs (dead after Breg hoist).
__global__ __launch_bounds__(512, 2) void k_all(
        const float* __restrict__ ctc,  const float* __restrict__ aif,
        const float* __restrict__ timev,const float* __restrict__ lam,
        const float* __restrict__ eta,  unsigned int* __restrict__ flags,
        f32x4* __restrict__ partials,   float* __restrict__ out) {
    union SharedPool {
        i32x4 Bs[NSLOT * 64];        // 43 KB  (phase 1: B build)
        f32x4 cbuf[8][64][13];       // 106 KB (phase 2: acc exchange, padded)
    };
    __shared__ SharedPool sp;
    __shared__ float tshs[512];          // 2 KB
    __shared__ float aifos[512];         // 2 KB
    __shared__ float a_s[64], t_s[64];
    __shared__ f32x4 red[4];

    const int tid  = threadIdx.x;
    const int lane = tid & 63;
    const int wid  = tid >> 6;           // 0..7
    const int par  = wid & 1;            // K parity
    const int pair = wid >> 1;           // 0..3
    const int q = lane >> 4, n = lane & 15;
    const int pixbase = blockIdx.x * 64 + pair * 16;
    const int mypix   = pixbase + n;

    // ---- phase A: local setup ----
    if (tid < 64) { a_s[tid] = aif[tid]; t_s[tid] = timev[tid]; }
    float A  = eta[mypix];
    float K  = eta[NPIX + mypix];
    float T0 = eta[2*NPIX + mypix];
    const float pA = A, pK = K, pT = T0;
    __syncthreads();
    {
        float m5a = 0.2f * (a_s[0]+a_s[1]+a_s[2]+a_s[3]+a_s[4]);
        float t16;
        {   // t_os[16]: x = (16-3.5)/8 = 1.5625
            float xx = 1.5625f; int i0 = (int)xx; float f = xx - (float)i0;
            t16 = t_s[i0]*(1.0f-f) + t_s[i0+1]*f;
        }
        int i = tid;   // 0..511
        float x = ((float)i - 3.5f) * 0.125f;
        float ao, to;
        if (x <= 0.0f)       { ao = a_s[0]  - m5a; to = t_s[0];  }
        else if (x >= 63.0f) { ao = a_s[63] - m5a; to = t_s[63]; }
        else {
            int i0 = (int)x; float f = x - (float)i0;
            ao = (a_s[i0]-m5a)*(1.0f-f) + (a_s[i0+1]-m5a)*f;
            to = t_s[i0]*(1.0f-f) + t_s[i0+1]*f;
        }
        aifos[i] = ao;
        tshs[i]  = to - t16;
    }

    // ctc_dc (all waves): dcreg[nt][reg] = dc[p=q*4+reg][d=nt*16+n]
    float dcreg[4][4];
    #pragma unroll
    for (int reg = 0; reg < 4; ++reg) {
        const float* cp = ctc + (pixbase + q*4 + reg) * T_IN;
        float m5 = 0.2f * (cp[0]+cp[1]+cp[2]+cp[3]+cp[4]);
        #pragma unroll
        for (int nt = 0; nt < 4; ++nt) {
            int d = nt*16 + n;
            float cc = cp[d] - m5;
            float cm = cp[(d > 0) ? d-1 : 0] - m5;
            dcreg[nt][reg] = (d == 0) ? cc : (0.4375f*cm + 0.5625f*cc);
        }
    }

    // block partials (even waves only, to count each pixel once):
    if (par == 0) {
        float vs = 0.f;
        #pragma unroll
        for (int nt = 0; nt < 4; ++nt)
            #pragma unroll
            for (int r2 = 0; r2 < 4; ++r2) vs += dcreg[nt][r2]*dcreg[nt][r2];
        f32x4 pv = (f32x4){vs, 0.25f*A*A, 0.25f*K*K, 0.25f*T0*T0};
        #pragma unroll
        for (int m = 1; m < 64; m <<= 1) {
            pv.x += __shfl_xor(pv.x, m); pv.y += __shfl_xor(pv.y, m);
            pv.z += __shfl_xor(pv.z, m); pv.w += __shfl_xor(pv.w, m);
        }
        if (lane == 0) red[pair] = pv;
    }
    __syncthreads();
    if (tid == 0) {
        f32x4 s = red[0] + red[1] + red[2] + red[3];
        partials[blockIdx.x] = s;
        __threadfence();
        __hip_atomic_store(&flags[blockIdx.x], MAGIC, __ATOMIC_RELEASE,
                           __HIP_MEMORY_SCOPE_AGENT);
    }

    // ---- build B tiles in LDS (overlaps barrier skew), RTN ----
    for (int idx = tid; idx < NSLOT * 64; idx += 512) {
        int slot = idx >> 6, l = idx & 63;
        int kt, nt;
        if (slot < 20)      { kt = slot >> 2; nt = slot & 3; }
        else if (slot < 32) { int s = slot - 20; int d3 = s / 3; kt = 5 + d3; nt = 1 + (s - 3*d3); }
        else if (slot < 40) { int s = slot - 32; kt = 9 + (s >> 1); nt = 2 + (s & 1); }
        else                { kt = 13 + (slot - 40); nt = 3; }
        int kbase = 32*kt + 8*(l >> 4);
        int m = 16 + 8 * (16*nt + (l & 15));   // m_d = 16+8d
        H8 bh;
        #pragma unroll
        for (int jj = 0; jj < 4; ++jj) {
            float v[2];
            #pragma unroll
            for (int h = 0; h < 2; ++h) {
                int k  = kbase + 2*jj + h;
                int ai = m - k;
                float s2 = 1.0f / (1.0f + __expf(-500.0f * tshs[k]));
                v[h] = (ai >= 0 && ai < 512) ? s2 * aifos[ai] * 0.125f : 0.0f;
            }
            bh.h2[jj] = (fp16x2){(__fp16)v[0], (__fp16)v[1]};   // RTN
        }
        sp.Bs[idx] = bh.i4;
    }
    __syncthreads();

    // ---- hoist this wave's K-half of B into registers ----
    i32x4 Breg[23];
    if (par == 0) {
        #pragma unroll
        for (int s = 0; s < 23; ++s) Breg[s] = sp.Bs[SLOTS[0][s]*64 + lane];
    } else {
        #pragma unroll
        for (int s = 0; s < 20; ++s) Breg[s] = sp.Bs[SLOTS[1][s]*64 + lane];
    }

    // ---- grid barrier: threads 0..255 watch flags ----
    if (tid < 256)
        while (__hip_atomic_load(&flags[tid], __ATOMIC_ACQUIRE,
                                 __HIP_MEMORY_SCOPE_AGENT) != MAGIC)
            __builtin_amdgcn_s_sleep(2);
    __syncthreads();   // Bs dead beyond this point -> cbuf may reuse the space

    // ---- reduce the 256 partials ----
    f32x4 tot = partials[lane] + partials[64+lane] + partials[128+lane]
              + partials[192+lane];
    #pragma unroll
    for (int m = 1; m < 64; m <<= 1) {
        tot.x += __shfl_xor(tot.x, m); tot.y += __shfl_xor(tot.y, m);
        tot.z += __shfl_xor(tot.z, m); tot.w += __shfl_xor(tot.w, m);
    }
    float spl;
    {
        float xl = lam[0];
        spl = (xl > 0.0f) ? (xl + log1pf(__expf(-xl))) : log1pf(__expf(xl));
    }
    const float cdc2 = 2.0f / tot.x;
    const float rgA  = 2.0f * spl / tot.y;
    const float rgK  = 2.0f * spl / tot.z;
    const float rgT  = 2.0f * spl / tot.w;

    #pragma unroll 1
    for (int it = 0; it < MAX_ITER; ++it) {
        f32x4 acc[3][4];
        #pragma unroll
        for (int f = 0; f < 3; ++f)
            #pragma unroll
            for (int t = 0; t < 4; ++t)
                acc[f][t] = (f32x4){0.f, 0.f, 0.f, 0.f};

        if (par == 0) kloop<0>(K, T0, q, tshs, Breg, acc);
        else          kloop<1>(K, T0, q, tshs, Breg, acc);

        // symmetric exchange: everyone writes own half, reads partner's
        #pragma unroll
        for (int f = 0; f < 3; ++f)
            #pragma unroll
            for (int t = 0; t < 4; ++t)
                sp.cbuf[wid][lane][f*4+t] = acc[f][t];
        __syncthreads();
        #pragma unroll
        for (int f = 0; f < 3; ++f)
            #pragma unroll
            for (int t = 0; t < 4; ++t)
                acc[f][t] += sp.cbuf[wid ^ 1][lane][f*4+t];
        __syncthreads();   // WAR guard before next iteration's writes

        // ---- epilogue (both waves, identical math -> identical eta) ----
        float Ap[4];
        #pragma unroll
        for (int rr2 = 0; rr2 < 4; ++rr2) Ap[rr2] = __shfl(A, q*4 + rr2);

        float SA[4], SK[4], ST[4];
        #pragma unroll
        for (int r2 = 0; r2 < 4; ++r2) { SA[r2]=0.f; SK[r2]=0.f; ST[r2]=0.f; }
        #pragma unroll
        for (int nt = 0; nt < 4; ++nt)
            #pragma unroll
            for (int r2 = 0; r2 < 4; ++r2) {
                float Y0 = acc[0][nt][r2], Y1 = acc[1][nt][r2], Y2 = acc[2][nt][r2];
                float rr = fmaf(Ap[r2], Y0, -dcreg[nt][r2]);   // est - dc
                SA[r2] = fmaf(rr, Y0, SA[r2]);
                SK[r2] = fmaf(rr, Y1, SK[r2]);
                ST[r2] = fmaf(rr, Y2, ST[r2]);
            }
        #pragma unroll
        for (int r2 = 0; r2 < 4; ++r2)
            #pragma unroll
            for (int m = 1; m < 16; m <<= 1) {
                SA[r2] += __shfl_xor(SA[r2], m);
                SK[r2] += __shfl_xor(SK[r2], m);
                ST[r2] += __shfl_xor(ST[r2], m);
            }
        int src = (n >> 2) * 16;
        float GA = 0.f, GK = 0.f, GT = 0.f;
        #pragma unroll
        for (int r2 = 0; r2 < 4; ++r2) {
            float tA = __shfl(SA[r2], src);
            float tK = __shfl(SK[r2], src);
            float tT = __shfl(ST[r2], src);
            if ((n & 3) == r2) { GA = tA; GK = tK; GT = tT; }
        }

        float gA = fmaf(rgA, A  - pA, cdc2 * GA)         + 2.0f * fminf(A,  0.f);
        float gK = fmaf(rgK, K  - pK, cdc2 * A * GK)     + 2.0f * fminf(K,  0.f);
        float gT = fmaf(rgT, T0 - pT, cdc2 * A * K * GT) + 2.0f * fminf(T0, 0.f);
        A  -= 0.1f * gA;
        K  -= 0.1f * gK;
        T0 -= 0.1f * gT;
    }

    if (par == 0 && lane < 16) {
        out[mypix]          = A;
        out[NPIX + mypix]   = K;
        out[2*NPIX + mypix] = T0;
    }
}

// -------------------------------------------------------------- launch ------
extern "C" void kernel_launch(void* const* d_in, const int* in_sizes, int n_in,
                              void* d_out, int out_size, void* d_ws, size_t ws_size,
                              hipStream_t stream) {
    const float* ctc   = (const float*)d_in[0];
    const float* aif   = (const float*)d_in[1];
    const float* timev = (const float*)d_in[2];
    const float* eta   = (const float*)d_in[4];
    const float* lam   = (const float*)d_in[5];
    float* out = (float*)d_out;
    // ws layout: [0..4095]  f32x4 partials[256]
    //            [4096..5119] u32 flags[256]   (poison 0xAA... != MAGIC)
    f32x4*        partials = (f32x4*)d_ws;
    unsigned int* flags    = (unsigned int*)((char*)d_ws + 4096);

    k_all<<<NPIX / 64, 512, 0, stream>>>(ctc, aif, timev, lam, eta,
                                         flags, partials, out);
}

// Round 12
// 116.418 us; speedup vs baseline: 1.1015x; 1.1015x over previous
//
#include <hip/hip_runtime.h>
#include <math.h>

#define T_IN 64
#define NPIX 16384
#define MAX_ITER 10
#define NSLOT 43
#define MAGIC 0x13579BDFu

typedef _Float16 half8_t __attribute__((ext_vector_type(8)));
typedef __fp16   fp16x2  __attribute__((ext_vector_type(2)));
typedef float    f32x4   __attribute__((ext_vector_type(4)));
typedef int      i32x4   __attribute__((ext_vector_type(4)));

union H8 { half8_t v; fp16x2 h2[4]; i32x4 i4; };

__device__ __forceinline__ float rcp_fast(float x) { return __builtin_amdgcn_rcpf(x); }

// ---------------------------------------------------------------- all -------
// Single dispatch, grid 256 x 256 (1 wave/SIMD — R10/R11 showed cross-wave
// K-split costs more than the occupancy gains). R12: hot-loop diet —
// tsh hoisted to registers (f32 seeds + f16x2 pairs), d1 in packed f16,
// acc zero-init folded into kt==0 MFMA C-operand.
__global__ __launch_bounds__(256, 1) void k_all(
        const float* __restrict__ ctc,  const float* __restrict__ aif,
        const float* __restrict__ timev,const float* __restrict__ lam,
        const float* __restrict__ eta,  unsigned int* __restrict__ flags,
        f32x4* __restrict__ partials,   float* __restrict__ out) {
    __shared__ i32x4 Bs[NSLOT * 64];   // 43 KB
    __shared__ float tshs[512];        // 2 KB
    __shared__ float aifos[512];       // 2 KB
    __shared__ float a_s[64], t_s[64];
    __shared__ f32x4 red[4];

    const int tid  = threadIdx.x;
    const int lane = tid & 63;
    const int wid  = tid >> 6;
    const int q = lane >> 4, n = lane & 15;
    const int pixbase = blockIdx.x * 64 + wid * 16;
    const int mypix   = pixbase + n;

    // ---- phase A: local setup ----
    if (tid < 64) { a_s[tid] = aif[tid]; t_s[tid] = timev[tid]; }
    float A  = eta[mypix];
    float K  = eta[NPIX + mypix];
    float T0 = eta[2*NPIX + mypix];
    const float pA = A, pK = K, pT = T0;
    __syncthreads();
    {
        float m5a = 0.2f * (a_s[0]+a_s[1]+a_s[2]+a_s[3]+a_s[4]);
        float t16;
        {   // t_os[16]: x = (16-3.5)/8 = 1.5625
            float xx = 1.5625f; int i0 = (int)xx; float f = xx - (float)i0;
            t16 = t_s[i0]*(1.0f-f) + t_s[i0+1]*f;
        }
        #pragma unroll
        for (int rep = 0; rep < 2; ++rep) {
            int i = tid + 256*rep;
            float x = ((float)i - 3.5f) * 0.125f;
            float ao, to;
            if (x <= 0.0f)       { ao = a_s[0]  - m5a; to = t_s[0];  }
            else if (x >= 63.0f) { ao = a_s[63] - m5a; to = t_s[63]; }
            else {
                int i0 = (int)x; float f = x - (float)i0;
                ao = (a_s[i0]-m5a)*(1.0f-f) + (a_s[i0+1]-m5a)*f;
                to = t_s[i0]*(1.0f-f) + t_s[i0+1]*f;
            }
            aifos[i] = ao;
            tshs[i]  = to - t16;
        }
    }

    // ctc_dc in C-layout registers: dcreg[nt][reg] = dc[p=q*4+reg][d=nt*16+n]
    float dcreg[4][4];
    #pragma unroll
    for (int reg = 0; reg < 4; ++reg) {
        const float* cp = ctc + (pixbase + q*4 + reg) * T_IN;
        float m5 = 0.2f * (cp[0]+cp[1]+cp[2]+cp[3]+cp[4]);
        #pragma unroll
        for (int nt = 0; nt < 4; ++nt) {
            int d = nt*16 + n;
            float cc = cp[d] - m5;
            float cm = cp[(d > 0) ? d-1 : 0] - m5;
            dcreg[nt][reg] = (d == 0) ? cc : (0.4375f*cm + 0.5625f*cc);
        }
    }

    // block partials: C_dc = sum dcreg^2; C_nn: each pixel on 4 lanes -> /4
    {
        float vs = 0.f;
        #pragma unroll
        for (int nt = 0; nt < 4; ++nt)
            #pragma unroll
            for (int r2 = 0; r2 < 4; ++r2) vs += dcreg[nt][r2]*dcreg[nt][r2];
        f32x4 pv = (f32x4){vs, 0.25f*A*A, 0.25f*K*K, 0.25f*T0*T0};
        #pragma unroll
        for (int m = 1; m < 64; m <<= 1) {
            pv.x += __shfl_xor(pv.x, m); pv.y += __shfl_xor(pv.y, m);
            pv.z += __shfl_xor(pv.z, m); pv.w += __shfl_xor(pv.w, m);
        }
        if (lane == 0) red[wid] = pv;
    }
    __syncthreads();
    if (tid == 0) {
        f32x4 s = red[0] + red[1] + red[2] + red[3];
        partials[blockIdx.x] = s;
        __threadfence();
        __hip_atomic_store(&flags[blockIdx.x], MAGIC, __ATOMIC_RELEASE,
                           __HIP_MEMORY_SCOPE_AGENT);
    }

    // ---- build B tiles in LDS (overlaps barrier skew), RTN ----
    for (int idx = tid; idx < NSLOT * 64; idx += 256) {
        int slot = idx >> 6, l = idx & 63;
        int kt, nt;
        if (slot < 20)      { kt = slot >> 2; nt = slot & 3; }
        else if (slot < 32) { int s = slot - 20; int d3 = s / 3; kt = 5 + d3; nt = 1 + (s - 3*d3); }
        else if (slot < 40) { int s = slot - 32; kt = 9 + (s >> 1); nt = 2 + (s & 1); }
        else                { kt = 13 + (slot - 40); nt = 3; }
        int kbase = 32*kt + 8*(l >> 4);
        int m = 16 + 8 * (16*nt + (l & 15));   // m_d = 16+8d
        H8 bh;
        #pragma unroll
        for (int jj = 0; jj < 4; ++jj) {
            float v[2];
            #pragma unroll
            for (int h = 0; h < 2; ++h) {
                int k  = kbase + 2*jj + h;
                int ai = m - k;
                float s2 = 1.0f / (1.0f + __expf(-500.0f * tshs[k]));
                v[h] = (ai >= 0 && ai < 512) ? s2 * aifos[ai] * 0.125f : 0.0f;
            }
            bh.h2[jj] = (fp16x2){(__fp16)v[0], (__fp16)v[1]};   // RTN
        }
        Bs[idx] = bh.i4;
    }
    __syncthreads();

    // ---- hoist B into registers (iteration-invariant) ----
    i32x4 Breg[NSLOT];
    #pragma unroll
    for (int s = 0; s < NSLOT; ++s) Breg[s] = Bs[s*64 + lane];

    // ---- hoist tsh into registers (iteration-invariant, per-lane q) ----
    float  d10b[16];        // chain seeds: tsh[32kt+8q]
    fp16x2 tshh[16][4];     // f16 pairs for d1h = T0h2 - tshh
    float  tse0[8], tse15[8];  // full f32 for the edge-exp path
    #pragma unroll
    for (int kt = 0; kt < 16; ++kt) {
        f32x4 tv0 = *(const f32x4*)&tshs[32*kt + 8*q];
        f32x4 tv1 = *(const f32x4*)&tshs[32*kt + 8*q + 4];
        d10b[kt] = tv0[0];
        tshh[kt][0] = __builtin_amdgcn_cvt_pkrtz(tv0[0], tv0[1]);
        tshh[kt][1] = __builtin_amdgcn_cvt_pkrtz(tv0[2], tv0[3]);
        tshh[kt][2] = __builtin_amdgcn_cvt_pkrtz(tv1[0], tv1[1]);
        tshh[kt][3] = __builtin_amdgcn_cvt_pkrtz(tv1[2], tv1[3]);
        if (kt == 0) {
            tse0[0]=tv0[0]; tse0[1]=tv0[1]; tse0[2]=tv0[2]; tse0[3]=tv0[3];
            tse0[4]=tv1[0]; tse0[5]=tv1[1]; tse0[6]=tv1[2]; tse0[7]=tv1[3];
        }
        if (kt == 15) {
            tse15[0]=tv0[0]; tse15[1]=tv0[1]; tse15[2]=tv0[2]; tse15[3]=tv0[3];
            tse15[4]=tv1[0]; tse15[5]=tv1[1]; tse15[6]=tv1[2]; tse15[7]=tv1[3];
        }
    }

    // ---- grid barrier: thread t watches flags[t] ----
    while (__hip_atomic_load(&flags[tid], __ATOMIC_ACQUIRE,
                             __HIP_MEMORY_SCOPE_AGENT) != MAGIC)
        __builtin_amdgcn_s_sleep(2);
    __syncthreads();

    // ---- reduce the 256 partials ----
    f32x4 tot = partials[lane] + partials[64+lane] + partials[128+lane]
              + partials[192+lane];
    #pragma unroll
    for (int m = 1; m < 64; m <<= 1) {
        tot.x += __shfl_xor(tot.x, m); tot.y += __shfl_xor(tot.y, m);
        tot.z += __shfl_xor(tot.z, m); tot.w += __shfl_xor(tot.w, m);
    }
    float spl;
    {
        float xl = lam[0];
        spl = (xl > 0.0f) ? (xl + log1pf(__expf(-xl))) : log1pf(__expf(xl));
    }
    const float cdc2 = 2.0f / tot.x;
    const float rgA  = 2.0f * spl / tot.y;
    const float rgK  = 2.0f * spl / tot.z;
    const float rgT  = 2.0f * spl / tot.w;

    constexpr int NTMIN[16] = {0,0,0,0,0,1,1,1,1,2,2,2,2,3,3,3};
    constexpr int TOFS[16]  = {0,4,8,12,16,20,23,26,29,32,34,36,38,40,41,42};
    const f32x4 Z = (f32x4){0.f, 0.f, 0.f, 0.f};

    #pragma unroll 1
    for (int it = 0; it < MAX_ITER; ++it) {
        f32x4 acc[3][4];      // initialized via kt==0 MFMA with C=Z

        float nK = -K;
        float r  = __expf(0.125f * K);     // x ratio per t-step
        fp16x2 T0h2;
        { __fp16 t0h = (__fp16)T0; T0h2 = (fp16x2){t0h, t0h}; }

        #pragma unroll
        for (int kt = 0; kt < 16; ++kt) {
            float x[8];
            float d10 = T0 - d10b[kt];
            if (kt == 0 || kt == 15) {
                bool edge = (kt == 0) ? (q == 0) : (q == 3);  // flat tsh samples
                if (edge) {
                    const float* te = (kt == 0) ? tse0 : tse15;
                    #pragma unroll
                    for (int j = 0; j < 8; ++j) x[j] = __expf(nK * (T0 - te[j]));
                } else {
                    x[0] = __expf(nK * d10);
                    #pragma unroll
                    for (int j = 1; j < 8; ++j) x[j] = x[j-1] * r;
                }
            } else {
                x[0] = __expf(nK * d10);
                #pragma unroll
                for (int j = 1; j < 8; ++j) x[j] = x[j-1] * r;
            }
            H8 F0h, F1h, F2h;
            #pragma unroll
            for (int jj = 0; jj < 4; ++jj) {
                float s1a = rcp_fast(1.0f + x[2*jj]);
                float s1b = rcp_fast(1.0f + x[2*jj+1]);
                fp16x2 sh  = (fp16x2){(__fp16)s1a, (__fp16)s1b};   // RTN
                fp16x2 eh  = sh - sh*sh;                           // v_pk f16
                fp16x2 d1h = T0h2 - tshh[kt][jj];                  // v_pk_sub
                F0h.h2[jj] = sh;
                F1h.h2[jj] = eh * d1h;
                F2h.h2[jj] = eh;
            }
            #pragma unroll
            for (int nt = NTMIN[kt]; nt < 4; ++nt) {
                int slot = TOFS[kt] + nt - NTMIN[kt];
                H8 bh; bh.i4 = Breg[slot];
                if (kt == 0) {
                    acc[0][nt] = __builtin_amdgcn_mfma_f32_16x16x32_f16(F0h.v, bh.v, Z, 0, 0, 0);
                    acc[1][nt] = __builtin_amdgcn_mfma_f32_16x16x32_f16(F1h.v, bh.v, Z, 0, 0, 0);
                    acc[2][nt] = __builtin_amdgcn_mfma_f32_16x16x32_f16(F2h.v, bh.v, Z, 0, 0, 0);
                } else {
                    acc[0][nt] = __builtin_amdgcn_mfma_f32_16x16x32_f16(F0h.v, bh.v, acc[0][nt], 0, 0, 0);
                    acc[1][nt] = __builtin_amdgcn_mfma_f32_16x16x32_f16(F1h.v, bh.v, acc[1][nt], 0, 0, 0);
                    acc[2][nt] = __builtin_amdgcn_mfma_f32_16x16x32_f16(F2h.v, bh.v, acc[2][nt], 0, 0, 0);
                }
            }
        }

        // ---- epilogue: residuals, per-pixel gradient dots, reduce, route ----
        float Ap[4];
        #pragma unroll
        for (int rr2 = 0; rr2 < 4; ++rr2) Ap[rr2] = __shfl(A, q*4 + rr2);

        float SA[4], SK[4], ST[4];
        #pragma unroll
        for (int r2 = 0; r2 < 4; ++r2) { SA[r2]=0.f; SK[r2]=0.f; ST[r2]=0.f; }
        #pragma unroll
        for (int nt = 0; nt < 4; ++nt)
            #pragma unroll
            for (int r2 = 0; r2 < 4; ++r2) {
                float Y0 = acc[0][nt][r2], Y1 = acc[1][nt][r2], Y2 = acc[2][nt][r2];
                float rr = fmaf(Ap[r2], Y0, -dcreg[nt][r2]);   // est - dc
                SA[r2] = fmaf(rr, Y0, SA[r2]);
                SK[r2] = fmaf(rr, Y1, SK[r2]);
                ST[r2] = fmaf(rr, Y2, ST[r2]);
            }
        #pragma unroll
        for (int r2 = 0; r2 < 4; ++r2)
            #pragma unroll
            for (int m = 1; m < 16; m <<= 1) {
                SA[r2] += __shfl_xor(SA[r2], m);
                SK[r2] += __shfl_xor(SK[r2], m);
                ST[r2] += __shfl_xor(ST[r2], m);
            }
        // route: pixel p=n lives in group p>>2, slot p&3
        int src = (n >> 2) * 16;
        float GA = 0.f, GK = 0.f, GT = 0.f;
        #pragma unroll
        for (int r2 = 0; r2 < 4; ++r2) {
            float tA = __shfl(SA[r2], src);
            float tK = __shfl(SK[r2], src);
            float tT = __shfl(ST[r2], src);
            if ((n & 3) == r2) { GA = tA; GK = tK; GT = tT; }
        }

        float gA = fmaf(rgA, A  - pA, cdc2 * GA)         + 2.0f * fminf(A,  0.f);
        float gK = fmaf(rgK, K  - pK, cdc2 * A * GK)     + 2.0f * fminf(K,  0.f);
        float gT = fmaf(rgT, T0 - pT, cdc2 * A * K * GT) + 2.0f * fminf(T0, 0.f);
        A  -= 0.1f * gA;
        K  -= 0.1f * gK;
        T0 -= 0.1f * gT;
    }

    if (lane < 16) {
        out[mypix]          = A;
        out[NPIX + mypix]   = K;
        out[2*NPIX + mypix] = T0;
    }
}

// -------------------------------------------------------------- launch ------
extern "C" void kernel_launch(void* const* d_in, const int* in_sizes, int n_in,
                              void* d_out, int out_size, void* d_ws, size_t ws_size,
                              hipStream_t stream) {
    const float* ctc   = (const float*)d_in[0];
    const float* aif   = (const float*)d_in[1];
    const float* timev = (const float*)d_in[2];
    const float* eta   = (const float*)d_in[4];
    const float* lam   = (const float*)d_in[5];
    float* out = (float*)d_out;
    // ws layout: [0..4095]  f32x4 partials[256]
    //            [4096..5119] u32 flags[256]   (poison 0xAA... != MAGIC)
    f32x4*        partials = (f32x4*)d_ws;
    unsigned int* flags    = (unsigned int*)((char*)d_ws + 4096);

    k_all<<<NPIX / 64, 256, 0, stream>>>(ctc, aif, timev, lam, eta,
                                         flags, partials, out);
}

// Round 13
// 114.927 us; speedup vs baseline: 1.1158x; 1.0130x over previous
//
#include <hip/hip_runtime.h>
#include <math.h>

#define T_IN 64
#define NPIX 16384
#define MAX_ITER 10
#define NSLOT 43
#define MAGIC 0x13579BDFu

typedef _Float16 half8_t __attribute__((ext_vector_type(8)));
typedef __fp16   fp16x2  __attribute__((ext_vector_type(2)));
typedef float    f32x4   __attribute__((ext_vector_type(4)));
typedef int      i32x4   __attribute__((ext_vector_type(4)));

union H8 { half8_t v; fp16x2 h2[4]; i32x4 i4; };

__device__ __forceinline__ float rcp_fast(float x) { return __builtin_amdgcn_rcpf(x); }

// ---------------------------------------------------------------- all -------
// Single dispatch, grid 256 x 256 (1 wave/SIMD). R13: register diet —
// tshh f16 hoist (64 pinned VGPRs) replaced by arithmetic d1h rebuild
// (tsh step is exactly 0.125); x-chain split into two 3-mul chains
// (2 exps/tile); s1 f16 cvt via single cvt_pkrtz. Goal: give the
// scheduler room to interleave the 16 independent kt tiles.
__global__ __launch_bounds__(256, 1) void k_all(
        const float* __restrict__ ctc,  const float* __restrict__ aif,
        const float* __restrict__ timev,const float* __restrict__ lam,
        const float* __restrict__ eta,  unsigned int* __restrict__ flags,
        f32x4* __restrict__ partials,   float* __restrict__ out) {
    __shared__ i32x4 Bs[NSLOT * 64];   // 43 KB
    __shared__ float tshs[512];        // 2 KB
    __shared__ float aifos[512];       // 2 KB
    __shared__ float a_s[64], t_s[64];
    __shared__ f32x4 red[4];

    const int tid  = threadIdx.x;
    const int lane = tid & 63;
    const int wid  = tid >> 6;
    const int q = lane >> 4, n = lane & 15;
    const int pixbase = blockIdx.x * 64 + wid * 16;
    const int mypix   = pixbase + n;

    // ---- phase A: local setup ----
    if (tid < 64) { a_s[tid] = aif[tid]; t_s[tid] = timev[tid]; }
    float A  = eta[mypix];
    float K  = eta[NPIX + mypix];
    float T0 = eta[2*NPIX + mypix];
    const float pA = A, pK = K, pT = T0;
    __syncthreads();
    {
        float m5a = 0.2f * (a_s[0]+a_s[1]+a_s[2]+a_s[3]+a_s[4]);
        float t16;
        {   // t_os[16]: x = (16-3.5)/8 = 1.5625
            float xx = 1.5625f; int i0 = (int)xx; float f = xx - (float)i0;
            t16 = t_s[i0]*(1.0f-f) + t_s[i0+1]*f;
        }
        #pragma unroll
        for (int rep = 0; rep < 2; ++rep) {
            int i = tid + 256*rep;
            float x = ((float)i - 3.5f) * 0.125f;
            float ao, to;
            if (x <= 0.0f)       { ao = a_s[0]  - m5a; to = t_s[0];  }
            else if (x >= 63.0f) { ao = a_s[63] - m5a; to = t_s[63]; }
            else {
                int i0 = (int)x; float f = x - (float)i0;
                ao = (a_s[i0]-m5a)*(1.0f-f) + (a_s[i0+1]-m5a)*f;
                to = t_s[i0]*(1.0f-f) + t_s[i0+1]*f;
            }
            aifos[i] = ao;
            tshs[i]  = to - t16;
        }
    }

    // ctc_dc in C-layout registers: dcreg[nt][reg] = dc[p=q*4+reg][d=nt*16+n]
    float dcreg[4][4];
    #pragma unroll
    for (int reg = 0; reg < 4; ++reg) {
        const float* cp = ctc + (pixbase + q*4 + reg) * T_IN;
        float m5 = 0.2f * (cp[0]+cp[1]+cp[2]+cp[3]+cp[4]);
        #pragma unroll
        for (int nt = 0; nt < 4; ++nt) {
            int d = nt*16 + n;
            float cc = cp[d] - m5;
            float cm = cp[(d > 0) ? d-1 : 0] - m5;
            dcreg[nt][reg] = (d == 0) ? cc : (0.4375f*cm + 0.5625f*cc);
        }
    }

    // block partials: C_dc = sum dcreg^2; C_nn: each pixel on 4 lanes -> /4
    {
        float vs = 0.f;
        #pragma unroll
        for (int nt = 0; nt < 4; ++nt)
            #pragma unroll
            for (int r2 = 0; r2 < 4; ++r2) vs += dcreg[nt][r2]*dcreg[nt][r2];
        f32x4 pv = (f32x4){vs, 0.25f*A*A, 0.25f*K*K, 0.25f*T0*T0};
        #pragma unroll
        for (int m = 1; m < 64; m <<= 1) {
            pv.x += __shfl_xor(pv.x, m); pv.y += __shfl_xor(pv.y, m);
            pv.z += __shfl_xor(pv.z, m); pv.w += __shfl_xor(pv.w, m);
        }
        if (lane == 0) red[wid] = pv;
    }
    __syncthreads();
    if (tid == 0) {
        f32x4 s = red[0] + red[1] + red[2] + red[3];
        partials[blockIdx.x] = s;
        __threadfence();
        __hip_atomic_store(&flags[blockIdx.x], MAGIC, __ATOMIC_RELEASE,
                           __HIP_MEMORY_SCOPE_AGENT);
    }

    // ---- build B tiles in LDS (overlaps barrier skew), RTN ----
    for (int idx = tid; idx < NSLOT * 64; idx += 256) {
        int slot = idx >> 6, l = idx & 63;
        int kt, nt;
        if (slot < 20)      { kt = slot >> 2; nt = slot & 3; }
        else if (slot < 32) { int s = slot - 20; int d3 = s / 3; kt = 5 + d3; nt = 1 + (s - 3*d3); }
        else if (slot < 40) { int s = slot - 32; kt = 9 + (s >> 1); nt = 2 + (s & 1); }
        else                { kt = 13 + (slot - 40); nt = 3; }
        int kbase = 32*kt + 8*(l >> 4);
        int m = 16 + 8 * (16*nt + (l & 15));   // m_d = 16+8d
        H8 bh;
        #pragma unroll
        for (int jj = 0; jj < 4; ++jj) {
            float v[2];
            #pragma unroll
            for (int h = 0; h < 2; ++h) {
                int k  = kbase + 2*jj + h;
                int ai = m - k;
                float s2 = 1.0f / (1.0f + __expf(-500.0f * tshs[k]));
                v[h] = (ai >= 0 && ai < 512) ? s2 * aifos[ai] * 0.125f : 0.0f;
            }
            bh.h2[jj] = (fp16x2){(__fp16)v[0], (__fp16)v[1]};   // RTN
        }
        Bs[idx] = bh.i4;
    }
    __syncthreads();

    // ---- hoist B into registers (iteration-invariant) ----
    i32x4 Breg[NSLOT];
    #pragma unroll
    for (int s = 0; s < NSLOT; ++s) Breg[s] = Bs[s*64 + lane];

    // ---- hoist tsh seeds (iteration-invariant, per-lane q) ----
    float  d10b[16];           // chain seeds: tsh[32kt+8q]
    float  tse0[8], tse15[8];  // full f32 for the edge path
    #pragma unroll
    for (int kt = 0; kt < 16; ++kt) {
        d10b[kt] = tshs[32*kt + 8*q];
        if (kt == 0) {
            #pragma unroll
            for (int j = 0; j < 8; ++j) tse0[j] = tshs[8*q + j];
        }
        if (kt == 15) {
            #pragma unroll
            for (int j = 0; j < 8; ++j) tse15[j] = tshs[480 + 8*q + j];
        }
    }

    // ---- grid barrier: thread t watches flags[t] ----
    while (__hip_atomic_load(&flags[tid], __ATOMIC_ACQUIRE,
                             __HIP_MEMORY_SCOPE_AGENT) != MAGIC)
        __builtin_amdgcn_s_sleep(2);
    __syncthreads();

    // ---- reduce the 256 partials ----
    f32x4 tot = partials[lane] + partials[64+lane] + partials[128+lane]
              + partials[192+lane];
    #pragma unroll
    for (int m = 1; m < 64; m <<= 1) {
        tot.x += __shfl_xor(tot.x, m); tot.y += __shfl_xor(tot.y, m);
        tot.z += __shfl_xor(tot.z, m); tot.w += __shfl_xor(tot.w, m);
    }
    float spl;
    {
        float xl = lam[0];
        spl = (xl > 0.0f) ? (xl + log1pf(__expf(-xl))) : log1pf(__expf(xl));
    }
    const float cdc2 = 2.0f / tot.x;
    const float rgA  = 2.0f * spl / tot.y;
    const float rgK  = 2.0f * spl / tot.z;
    const float rgT  = 2.0f * spl / tot.w;

    constexpr int NTMIN[16] = {0,0,0,0,0,1,1,1,1,2,2,2,2,3,3,3};
    constexpr int TOFS[16]  = {0,4,8,12,16,20,23,26,29,32,34,36,38,40,41,42};
    const f32x4 Z = (f32x4){0.f, 0.f, 0.f, 0.f};
    const fp16x2 c1 = {(__fp16)0.25f, (__fp16)0.25f};
    const fp16x2 c2 = {(__fp16)0.50f, (__fp16)0.50f};
    const fp16x2 c3 = {(__fp16)0.75f, (__fp16)0.75f};

    #pragma unroll 1
    for (int it = 0; it < MAX_ITER; ++it) {
        f32x4 acc[3][4];      // initialized via kt==0 MFMA with C=Z

        float nK = -K;
        float r  = __expf(0.125f * K);     // x ratio per t-step

        #pragma unroll
        for (int kt = 0; kt < 16; ++kt) {
            float  x[8];
            fp16x2 d1h[4];
            float  d10 = T0 - d10b[kt];
            bool flat = (kt == 0 && q == 0) || (kt == 15 && q == 3);
            if (flat) {   // clamped tsh samples: full per-element path
                const float* te = (kt == 0) ? tse0 : tse15;
                #pragma unroll
                for (int j = 0; j < 8; ++j) x[j] = __expf(nK * (T0 - te[j]));
                #pragma unroll
                for (int jj = 0; jj < 4; ++jj)
                    d1h[jj] = __builtin_amdgcn_cvt_pkrtz(T0 - te[2*jj],
                                                         T0 - te[2*jj+1]);
            } else {      // arithmetic tsh: split chains + pk d1h rebuild
                x[0] = __expf(nK * d10);
                x[4] = __expf(nK * (d10 - 0.5f));
                x[1] = x[0]*r; x[2] = x[1]*r; x[3] = x[2]*r;
                x[5] = x[4]*r; x[6] = x[5]*r; x[7] = x[6]*r;
                fp16x2 D0 = __builtin_amdgcn_cvt_pkrtz(d10, d10 - 0.125f);
                d1h[0] = D0;
                d1h[1] = D0 - c1;
                d1h[2] = D0 - c2;
                d1h[3] = D0 - c3;
            }
            H8 F0h, F1h, F2h;
            #pragma unroll
            for (int jj = 0; jj < 4; ++jj) {
                float s1a = rcp_fast(1.0f + x[2*jj]);
                float s1b = rcp_fast(1.0f + x[2*jj+1]);
                fp16x2 sh = __builtin_amdgcn_cvt_pkrtz(s1a, s1b);
                fp16x2 eh = sh - sh*sh;                  // v_pk f16
                F0h.h2[jj] = sh;
                F1h.h2[jj] = eh * d1h[jj];
                F2h.h2[jj] = eh;
            }
            #pragma unroll
            for (int nt = NTMIN[kt]; nt < 4; ++nt) {
                int slot = TOFS[kt] + nt - NTMIN[kt];
                H8 bh; bh.i4 = Breg[slot];
                if (kt == 0) {
                    acc[0][nt] = __builtin_amdgcn_mfma_f32_16x16x32_f16(F0h.v, bh.v, Z, 0, 0, 0);
                    acc[1][nt] = __builtin_amdgcn_mfma_f32_16x16x32_f16(F1h.v, bh.v, Z, 0, 0, 0);
                    acc[2][nt] = __builtin_amdgcn_mfma_f32_16x16x32_f16(F2h.v, bh.v, Z, 0, 0, 0);
                } else {
                    acc[0][nt] = __builtin_amdgcn_mfma_f32_16x16x32_f16(F0h.v, bh.v, acc[0][nt], 0, 0, 0);
                    acc[1][nt] = __builtin_amdgcn_mfma_f32_16x16x32_f16(F1h.v, bh.v, acc[1][nt], 0, 0, 0);
                    acc[2][nt] = __builtin_amdgcn_mfma_f32_16x16x32_f16(F2h.v, bh.v, acc[2][nt], 0, 0, 0);
                }
            }
        }

        // ---- epilogue: residuals, per-pixel gradient dots, reduce, route ----
        float Ap[4];
        #pragma unroll
        for (int rr2 = 0; rr2 < 4; ++rr2) Ap[rr2] = __shfl(A, q*4 + rr2);

        float SA[4], SK[4], ST[4];
        #pragma unroll
        for (int r2 = 0; r2 < 4; ++r2) { SA[r2]=0.f; SK[r2]=0.f; ST[r2]=0.f; }
        #pragma unroll
        for (int nt = 0; nt < 4; ++nt)
            #pragma unroll
            for (int r2 = 0; r2 < 4; ++r2) {
                float Y0 = acc[0][nt][r2], Y1 = acc[1][nt][r2], Y2 = acc[2][nt][r2];
                float rr = fmaf(Ap[r2], Y0, -dcreg[nt][r2]);   // est - dc
                SA[r2] = fmaf(rr, Y0, SA[r2]);
                SK[r2] = fmaf(rr, Y1, SK[r2]);
                ST[r2] = fmaf(rr, Y2, ST[r2]);
            }
        #pragma unroll
        for (int r2 = 0; r2 < 4; ++r2)
            #pragma unroll
            for (int m = 1; m < 16; m <<= 1) {
                SA[r2] += __shfl_xor(SA[r2], m);
                SK[r2] += __shfl_xor(SK[r2], m);
                ST[r2] += __shfl_xor(ST[r2], m);
            }
        // route: pixel p=n lives in group p>>2, slot p&3
        int src = (n >> 2) * 16;
        float GA = 0.f, GK = 0.f, GT = 0.f;
        #pragma unroll
        for (int r2 = 0; r2 < 4; ++r2) {
            float tA = __shfl(SA[r2], src);
            float tK = __shfl(SK[r2], src);
            float tT = __shfl(ST[r2], src);
            if ((n & 3) == r2) { GA = tA; GK = tK; GT = tT; }
        }

        float gA = fmaf(rgA, A  - pA, cdc2 * GA)         + 2.0f * fminf(A,  0.f);
        float gK = fmaf(rgK, K  - pK, cdc2 * A * GK)     + 2.0f * fminf(K,  0.f);
        float gT = fmaf(rgT, T0 - pT, cdc2 * A * K * GT) + 2.0f * fminf(T0, 0.f);
        A  -= 0.1f * gA;
        K  -= 0.1f * gK;
        T0 -= 0.1f * gT;
    }

    if (lane < 16) {
        out[mypix]          = A;
        out[NPIX + mypix]   = K;
        out[2*NPIX + mypix] = T0;
    }
}

// -------------------------------------------------------------- launch ------
extern "C" void kernel_launch(void* const* d_in, const int* in_sizes, int n_in,
                              void* d_out, int out_size, void* d_ws, size_t ws_size,
                              hipStream_t stream) {
    const float* ctc   = (const float*)d_in[0];
    const float* aif   = (const float*)d_in[1];
    const float* timev = (const float*)d_in[2];
    const float* eta   = (const float*)d_in[4];
    const float* lam   = (const float*)d_in[5];
    float* out = (float*)d_out;
    // ws layout: [0..4095]  f32x4 partials[256]
    //            [4096..5119] u32 flags[256]   (poison 0xAA... != MAGIC)
    f32x4*        partials = (f32x4*)d_ws;
    unsigned int* flags    = (unsigned int*)((char*)d_ws + 4096);

    k_all<<<NPIX / 64, 256, 0, stream>>>(ctc, aif, timev, lam, eta,
                                         flags, partials, out);
}

// Round 14
// 114.546 us; speedup vs baseline: 1.1195x; 1.0033x over previous
//
#include <hip/hip_runtime.h>
#include <math.h>

#define T_IN 64
#define NPIX 16384
#define MAX_ITER 10
#define NSLOT 43
#define MAGIC 0x13579BDFu

typedef _Float16 half8_t __attribute__((ext_vector_type(8)));
typedef __fp16   fp16x2  __attribute__((ext_vector_type(2)));
typedef float    f32x4   __attribute__((ext_vector_type(4)));
typedef int      i32x4   __attribute__((ext_vector_type(4)));

union H8 { half8_t v; fp16x2 h2[4]; i32x4 i4; };

__device__ __forceinline__ float rcp_fast(float x) { return __builtin_amdgcn_rcpf(x); }

__constant__ constexpr int NTMIN[16] = {0,0,0,0,0,1,1,1,1,2,2,2,2,3,3,3};
__constant__ constexpr int TOFS[16]  = {0,4,8,12,16,20,23,26,29,32,34,36,38,40,41,42};

// ---- field build for tile KT (compile-time KT -> all array idx constant) ----
template<int KT>
__device__ __forceinline__ void buildTile(float T0, float nK, float r, int q,
        const float (&d10b)[16], const float (&tse0)[8], const float (&tse15)[8],
        H8& F0h, H8& F1h, H8& F2h) {
    float  x[8];
    fp16x2 d1h[4];
    float  d10 = T0 - d10b[KT];
    const fp16x2 c1 = {(__fp16)0.25f, (__fp16)0.25f};
    const fp16x2 c2 = {(__fp16)0.50f, (__fp16)0.50f};
    const fp16x2 c3 = {(__fp16)0.75f, (__fp16)0.75f};
    bool arith = true;
    if constexpr (KT == 0 || KT == 15) {
        bool flat = (KT == 0) ? (q == 0) : (q == 3);   // clamped tsh samples
        if (flat) {
            arith = false;
            const float* te;
            if constexpr (KT == 0) te = tse0; else te = tse15;
            #pragma unroll
            for (int j = 0; j < 8; ++j) x[j] = __expf(nK * (T0 - te[j]));
            #pragma unroll
            for (int jj = 0; jj < 4; ++jj)
                d1h[jj] = __builtin_amdgcn_cvt_pkrtz(T0 - te[2*jj],
                                                     T0 - te[2*jj+1]);
        }
    }
    if (arith) {   // arithmetic tsh (step 0.125): split chains + pk d1h rebuild
        x[0] = __expf(nK * d10);
        x[4] = __expf(nK * (d10 - 0.5f));
        x[1] = x[0]*r; x[2] = x[1]*r; x[3] = x[2]*r;
        x[5] = x[4]*r; x[6] = x[5]*r; x[7] = x[6]*r;
        fp16x2 D0 = __builtin_amdgcn_cvt_pkrtz(d10, d10 - 0.125f);
        d1h[0] = D0;
        d1h[1] = D0 - c1;
        d1h[2] = D0 - c2;
        d1h[3] = D0 - c3;
    }
    #pragma unroll
    for (int jj = 0; jj < 4; ++jj) {
        float s1a = rcp_fast(1.0f + x[2*jj]);
        float s1b = rcp_fast(1.0f + x[2*jj+1]);
        fp16x2 sh = __builtin_amdgcn_cvt_pkrtz(s1a, s1b);
        fp16x2 eh = sh - sh*sh;                  // v_pk f16
        F0h.h2[jj] = sh;
        F1h.h2[jj] = eh * d1h[jj];
        F2h.h2[jj] = eh;
    }
}

// ---- software pipeline: build tile KT+1, then MFMA tile KT ----
template<int KT>
struct Pipe {
    static __device__ __forceinline__ void run(float T0, float nK, float r, int q,
            const float (&d10b)[16], const float (&tse0)[8], const float (&tse15)[8],
            const i32x4 (&Breg)[NSLOT],
            H8 (&F0p)[2], H8 (&F1p)[2], H8 (&F2p)[2],
            f32x4 (&acc)[3][4]) {
        if constexpr (KT < 15)
            buildTile<KT+1>(T0, nK, r, q, d10b, tse0, tse15,
                            F0p[(KT+1)&1], F1p[(KT+1)&1], F2p[(KT+1)&1]);
        const f32x4 Z = (f32x4){0.f, 0.f, 0.f, 0.f};
        #pragma unroll
        for (int nt = NTMIN[KT]; nt < 4; ++nt) {
            int slot = TOFS[KT] + nt - NTMIN[KT];
            H8 bh; bh.i4 = Breg[slot];
            if constexpr (KT == 0) {
                acc[0][nt] = __builtin_amdgcn_mfma_f32_16x16x32_f16(F0p[0].v, bh.v, Z, 0, 0, 0);
                acc[1][nt] = __builtin_amdgcn_mfma_f32_16x16x32_f16(F1p[0].v, bh.v, Z, 0, 0, 0);
                acc[2][nt] = __builtin_amdgcn_mfma_f32_16x16x32_f16(F2p[0].v, bh.v, Z, 0, 0, 0);
            } else {
                acc[0][nt] = __builtin_amdgcn_mfma_f32_16x16x32_f16(F0p[KT&1].v, bh.v, acc[0][nt], 0, 0, 0);
                acc[1][nt] = __builtin_amdgcn_mfma_f32_16x16x32_f16(F1p[KT&1].v, bh.v, acc[1][nt], 0, 0, 0);
                acc[2][nt] = __builtin_amdgcn_mfma_f32_16x16x32_f16(F2p[KT&1].v, bh.v, acc[2][nt], 0, 0, 0);
            }
        }
        if constexpr (KT < 15)
            Pipe<KT+1>::run(T0, nK, r, q, d10b, tse0, tse15, Breg, F0p, F1p, F2p, acc);
    }
};

// ---------------------------------------------------------------- all -------
// Single dispatch, grid 256 x 256 (1 wave/SIMD). R14: explicit 2-stage
// software pipeline over kt tiles (build kt+1 fields, then MFMA kt) to
// hide the exp->chain->rcp->cvt latency behind the previous tile's MFMAs.
__global__ __launch_bounds__(256, 1) void k_all(
        const float* __restrict__ ctc,  const float* __restrict__ aif,
        const float* __restrict__ timev,const float* __restrict__ lam,
        const float* __restrict__ eta,  unsigned int* __restrict__ flags,
        f32x4* __restrict__ partials,   float* __restrict__ out) {
    __shared__ i32x4 Bs[NSLOT * 64];   // 43 KB
    __shared__ float tshs[512];        // 2 KB
    __shared__ float aifos[512];       // 2 KB
    __shared__ float a_s[64], t_s[64];
    __shared__ f32x4 red[4];

    const int tid  = threadIdx.x;
    const int lane = tid & 63;
    const int wid  = tid >> 6;
    const int q = lane >> 4, n = lane & 15;
    const int pixbase = blockIdx.x * 64 + wid * 16;
    const int mypix   = pixbase + n;

    // ---- phase A: local setup ----
    if (tid < 64) { a_s[tid] = aif[tid]; t_s[tid] = timev[tid]; }
    float A  = eta[mypix];
    float K  = eta[NPIX + mypix];
    float T0 = eta[2*NPIX + mypix];
    const float pA = A, pK = K, pT = T0;
    __syncthreads();
    {
        float m5a = 0.2f * (a_s[0]+a_s[1]+a_s[2]+a_s[3]+a_s[4]);
        float t16;
        {   // t_os[16]: x = (16-3.5)/8 = 1.5625
            float xx = 1.5625f; int i0 = (int)xx; float f = xx - (float)i0;
            t16 = t_s[i0]*(1.0f-f) + t_s[i0+1]*f;
        }
        #pragma unroll
        for (int rep = 0; rep < 2; ++rep) {
            int i = tid + 256*rep;
            float x = ((float)i - 3.5f) * 0.125f;
            float ao, to;
            if (x <= 0.0f)       { ao = a_s[0]  - m5a; to = t_s[0];  }
            else if (x >= 63.0f) { ao = a_s[63] - m5a; to = t_s[63]; }
            else {
                int i0 = (int)x; float f = x - (float)i0;
                ao = (a_s[i0]-m5a)*(1.0f-f) + (a_s[i0+1]-m5a)*f;
                to = t_s[i0]*(1.0f-f) + t_s[i0+1]*f;
            }
            aifos[i] = ao;
            tshs[i]  = to - t16;
        }
    }

    // ctc_dc in C-layout registers: dcreg[nt][reg] = dc[p=q*4+reg][d=nt*16+n]
    float dcreg[4][4];
    #pragma unroll
    for (int reg = 0; reg < 4; ++reg) {
        const float* cp = ctc + (pixbase + q*4 + reg) * T_IN;
        float m5 = 0.2f * (cp[0]+cp[1]+cp[2]+cp[3]+cp[4]);
        #pragma unroll
        for (int nt = 0; nt < 4; ++nt) {
            int d = nt*16 + n;
            float cc = cp[d] - m5;
            float cm = cp[(d > 0) ? d-1 : 0] - m5;
            dcreg[nt][reg] = (d == 0) ? cc : (0.4375f*cm + 0.5625f*cc);
        }
    }

    // block partials: C_dc = sum dcreg^2; C_nn: each pixel on 4 lanes -> /4
    {
        float vs = 0.f;
        #pragma unroll
        for (int nt = 0; nt < 4; ++nt)
            #pragma unroll
            for (int r2 = 0; r2 < 4; ++r2) vs += dcreg[nt][r2]*dcreg[nt][r2];
        f32x4 pv = (f32x4){vs, 0.25f*A*A, 0.25f*K*K, 0.25f*T0*T0};
        #pragma unroll
        for (int m = 1; m < 64; m <<= 1) {
            pv.x += __shfl_xor(pv.x, m); pv.y += __shfl_xor(pv.y, m);
            pv.z += __shfl_xor(pv.z, m); pv.w += __shfl_xor(pv.w, m);
        }
        if (lane == 0) red[wid] = pv;
    }
    __syncthreads();
    if (tid == 0) {
        f32x4 s = red[0] + red[1] + red[2] + red[3];
        partials[blockIdx.x] = s;
        __threadfence();
        __hip_atomic_store(&flags[blockIdx.x], MAGIC, __ATOMIC_RELEASE,
                           __HIP_MEMORY_SCOPE_AGENT);
    }

    // ---- build B tiles in LDS (overlaps barrier skew), RTN ----
    for (int idx = tid; idx < NSLOT * 64; idx += 256) {
        int slot = idx >> 6, l = idx & 63;
        int kt, nt;
        if (slot < 20)      { kt = slot >> 2; nt = slot & 3; }
        else if (slot < 32) { int s = slot - 20; int d3 = s / 3; kt = 5 + d3; nt = 1 + (s - 3*d3); }
        else if (slot < 40) { int s = slot - 32; kt = 9 + (s >> 1); nt = 2 + (s & 1); }
        else                { kt = 13 + (slot - 40); nt = 3; }
        int kbase = 32*kt + 8*(l >> 4);
        int m = 16 + 8 * (16*nt + (l & 15));   // m_d = 16+8d
        H8 bh;
        #pragma unroll
        for (int jj = 0; jj < 4; ++jj) {
            float v[2];
            #pragma unroll
            for (int h = 0; h < 2; ++h) {
                int k  = kbase + 2*jj + h;
                int ai = m - k;
                float s2 = 1.0f / (1.0f + __expf(-500.0f * tshs[k]));
                v[h] = (ai >= 0 && ai < 512) ? s2 * aifos[ai] * 0.125f : 0.0f;
            }
            bh.h2[jj] = (fp16x2){(__fp16)v[0], (__fp16)v[1]};   // RTN
        }
        Bs[idx] = bh.i4;
    }
    __syncthreads();

    // ---- hoist B into registers (iteration-invariant) ----
    i32x4 Breg[NSLOT];
    #pragma unroll
    for (int s = 0; s < NSLOT; ++s) Breg[s] = Bs[s*64 + lane];

    // ---- hoist tsh seeds (iteration-invariant, per-lane q) ----
    float  d10b[16];           // chain seeds: tsh[32kt+8q]
    float  tse0[8], tse15[8];  // full f32 for the edge path
    #pragma unroll
    for (int kt = 0; kt < 16; ++kt) d10b[kt] = tshs[32*kt + 8*q];
    #pragma unroll
    for (int j = 0; j < 8; ++j) { tse0[j] = tshs[8*q + j]; tse15[j] = tshs[480 + 8*q + j]; }

    // ---- grid barrier: thread t watches flags[t] ----
    while (__hip_atomic_load(&flags[tid], __ATOMIC_ACQUIRE,
                             __HIP_MEMORY_SCOPE_AGENT) != MAGIC)
        __builtin_amdgcn_s_sleep(2);
    __syncthreads();

    // ---- reduce the 256 partials ----
    f32x4 tot = partials[lane] + partials[64+lane] + partials[128+lane]
              + partials[192+lane];
    #pragma unroll
    for (int m = 1; m < 64; m <<= 1) {
        tot.x += __shfl_xor(tot.x, m); tot.y += __shfl_xor(tot.y, m);
        tot.z += __shfl_xor(tot.z, m); tot.w += __shfl_xor(tot.w, m);
    }
    float spl;
    {
        float xl = lam[0];
        spl = (xl > 0.0f) ? (xl + log1pf(__expf(-xl))) : log1pf(__expf(xl));
    }
    const float cdc2 = 2.0f / tot.x;
    const float rgA  = 2.0f * spl / tot.y;
    const float rgK  = 2.0f * spl / tot.z;
    const float rgT  = 2.0f * spl / tot.w;

    #pragma unroll 1
    for (int it = 0; it < MAX_ITER; ++it) {
        float nK = -K;
        float r  = __expf(0.125f * K);     // x ratio per t-step

        H8 F0p[2], F1p[2], F2p[2];
        f32x4 acc[3][4];                   // initialized in Pipe<0> with C=Z
        buildTile<0>(T0, nK, r, q, d10b, tse0, tse15, F0p[0], F1p[0], F2p[0]);
        Pipe<0>::run(T0, nK, r, q, d10b, tse0, tse15, Breg, F0p, F1p, F2p, acc);

        // ---- epilogue: residuals, per-pixel gradient dots, reduce, route ----
        float Ap[4];
        #pragma unroll
        for (int rr2 = 0; rr2 < 4; ++rr2) Ap[rr2] = __shfl(A, q*4 + rr2);

        float SA[4], SK[4], ST[4];
        #pragma unroll
        for (int r2 = 0; r2 < 4; ++r2) { SA[r2]=0.f; SK[r2]=0.f; ST[r2]=0.f; }
        #pragma unroll
        for (int nt = 0; nt < 4; ++nt)
            #pragma unroll
            for (int r2 = 0; r2 < 4; ++r2) {
                float Y0 = acc[0][nt][r2], Y1 = acc[1][nt][r2], Y2 = acc[2][nt][r2];
                float rr = fmaf(Ap[r2], Y0, -dcreg[nt][r2]);   // est - dc
                SA[r2] = fmaf(rr, Y0, SA[r2]);
                SK[r2] = fmaf(rr, Y1, SK[r2]);
                ST[r2] = fmaf(rr, Y2, ST[r2]);
            }
        #pragma unroll
        for (int r2 = 0; r2 < 4; ++r2)
            #pragma unroll
            for (int m = 1; m < 16; m <<= 1) {
                SA[r2] += __shfl_xor(SA[r2], m);
                SK[r2] += __shfl_xor(SK[r2], m);
                ST[r2] += __shfl_xor(ST[r2], m);
            }
        // route: pixel p=n lives in group p>>2, slot p&3
        int src = (n >> 2) * 16;
        float GA = 0.f, GK = 0.f, GT = 0.f;
        #pragma unroll
        for (int r2 = 0; r2 < 4; ++r2) {
            float tA = __shfl(SA[r2], src);
            float tK = __shfl(SK[r2], src);
            float tT = __shfl(ST[r2], src);
            if ((n & 3) == r2) { GA = tA; GK = tK; GT = tT; }
        }

        float gA = fmaf(rgA, A  - pA, cdc2 * GA)         + 2.0f * fminf(A,  0.f);
        float gK = fmaf(rgK, K  - pK, cdc2 * A * GK)     + 2.0f * fminf(K,  0.f);
        float gT = fmaf(rgT, T0 - pT, cdc2 * A * K * GT) + 2.0f * fminf(T0, 0.f);
        A  -= 0.1f * gA;
        K  -= 0.1f * gK;
        T0 -= 0.1f * gT;
    }

    if (lane < 16) {
        out[mypix]          = A;
        out[NPIX + mypix]   = K;
        out[2*NPIX + mypix] = T0;
    }
}

// -------------------------------------------------------------- launch ------
extern "C" void kernel_launch(void* const* d_in, const int* in_sizes, int n_in,
                              void* d_out, int out_size, void* d_ws, size_t ws_size,
                              hipStream_t stream) {
    const float* ctc   = (const float*)d_in[0];
    const float* aif   = (const float*)d_in[1];
    const float* timev = (const float*)d_in[2];
    const float* eta   = (const float*)d_in[4];
    const float* lam   = (const float*)d_in[5];
    float* out = (float*)d_out;
    // ws layout: [0..4095]  f32x4 partials[256]
    //            [4096..5119] u32 flags[256]   (poison 0xAA... != MAGIC)
    f32x4*        partials = (f32x4*)d_ws;
    unsigned int* flags    = (unsigned int*)((char*)d_ws + 4096);

    k_all<<<NPIX / 64, 256, 0, stream>>>(ctc, aif, timev, lam, eta,
                                         flags, partials, out);
}